// Round 5
// baseline (328.593 us; speedup 1.0000x reference)
//
#include <hip/hip_runtime.h>

#define S_ 4096
#define H_ 8

typedef __attribute__((ext_vector_type(8))) short short8;
typedef __attribute__((ext_vector_type(4))) float f32x4;

static __device__ __forceinline__ float bf2f(unsigned short u) {
  union { unsigned int i; float f; } v; v.i = ((unsigned int)u) << 16; return v.f;
}
static __device__ __forceinline__ unsigned short f2bf(float f) {
  union { float f; unsigned int i; } v; v.f = f;
  unsigned int r = v.i + 0x7FFFu + ((v.i >> 16) & 1u);
  return (unsigned short)(r >> 16);
}

#define LOAD_LDS16(g, l) __builtin_amdgcn_global_load_lds( \
    (const __attribute__((address_space(1))) void*)(g),     \
    (__attribute__((address_space(3))) void*)(l), 16, 0, 0)

// ---------------------------------------------------------------------------
__global__ __launch_bounds__(256) void cast_x_kernel(
    const float* __restrict__ x, unsigned short* __restrict__ xb) {
  int i = (blockIdx.x * 256 + threadIdx.x) * 4;
  float4 v = *(const float4*)(x + i);
  ushort4 o;
  o.x = f2bf(v.x); o.y = f2bf(v.y); o.z = f2bf(v.z); o.w = f2bf(v.w);
  *(ushort4*)(xb + i) = o;
}

// Wq/bq pre-scaled by 0.125 (= 1/sqrt(64), exact in bf16)
__global__ __launch_bounds__(256) void cast_w_kernel(
    const float* __restrict__ Wq, const float* __restrict__ Wk,
    const float* __restrict__ Wv, const float* __restrict__ Wo,
    const float* __restrict__ bq, const float* __restrict__ bk,
    const float* __restrict__ bv,
    unsigned short* __restrict__ Wcat, unsigned short* __restrict__ Wob,
    float* __restrict__ bcat) {
  int i = blockIdx.x * 256 + threadIdx.x;  // 0..262143
  Wcat[i]          = f2bf(Wq[i] * 0.125f);
  Wcat[262144 + i] = f2bf(Wk[i]);
  Wcat[524288 + i] = f2bf(Wv[i]);
  Wob[i]           = f2bf(Wo[i]);
  if (i < 512) { bcat[i] = bq[i] * 0.125f; bcat[512 + i] = bk[i]; bcat[1024 + i] = bv[i]; }
}

// ---------------------------------------------------------------------------
// C[m][n] = sum_k A[m][k]*Bw[n][k] + bias[n], K=512, row-major operands.
// BM=BN=256, BK=32, 8 waves (2Mx4N), per-wave 128x64 (8x4 frags 16x16x32).
// 4-slot LDS ring (STATIC 128 KiB), depth-2 prefetch, counted vmcnt(8).
// LDS swizzle: slot = chunk ^ (row&3); applied on gload SOURCE (inverse)
// and ds_read address (both-sides rule #21). gload dest stays linear.
template<int OUT_BF16, int NBX>
__global__ __launch_bounds__(512, 2) void gemm256(
    const unsigned short* __restrict__ A,
    const unsigned short* __restrict__ Bw,
    const float* __restrict__ bias,
    void* __restrict__ Cv) {
  __shared__ unsigned short lds[65536];  // 4 slots x (A 8192 + B 8192) ushorts
  const int N = NBX * 256;
  const int NWG = 128 * NBX;

  const int tid = threadIdx.x;
  const int lane = tid & 63;
  const int wv = tid >> 6;        // 0..7
  const int wm = wv >> 2;         // 0..1
  const int wn = wv & 3;          // 0..3
  const int r = lane & 15;
  const int g = lane >> 4;        // 0..3

  // XCD-aware swizzle (NWG % 8 == 0 -> bijective)
  int id = blockIdx.x;
  id = (id & 7) * (NWG >> 3) + (id >> 3);
  const int by = id / NBX, bx = id % NBX;
  const int m0 = by * 256, n0 = bx * 256;

  // --- bias preload (pin BEFORE staging so vmcnt FIFO math stays exact)
  float bcol[4];
#pragma unroll
  for (int nj = 0; nj < 4; ++nj) bcol[nj] = bias[n0 + wn * 64 + nj * 16 + r];
  asm volatile("" : "+v"(bcol[0]), "+v"(bcol[1]), "+v"(bcol[2]), "+v"(bcol[3]));

  // --- staging addresses (per wave: 2 gloads for A, 2 for B per K-tile)
  const int srow = lane >> 2;                 // 0..15
  const int ccs = (lane & 3) ^ (srow & 3);    // inverse-swizzled source chunk
  const int rA0 = (wv * 2 + 0) * 16 + srow;   // 0..255
  const int rA1 = (wv * 2 + 1) * 16 + srow;
  const unsigned short* gA0 = A + (size_t)(m0 + rA0) * 512 + ccs * 8;
  const unsigned short* gA1 = A + (size_t)(m0 + rA1) * 512 + ccs * 8;
  const unsigned short* gB0 = Bw + (size_t)(n0 + rA0) * 512 + ccs * 8;
  const unsigned short* gB1 = Bw + (size_t)(n0 + rA1) * 512 + ccs * 8;
  const int ldsA0 = (wv * 2 + 0) * 512;       // ushort offset in A area
  const int ldsA1 = (wv * 2 + 1) * 512;

  // --- read addresses (swizzled): lane gets k-chunk g of its row
  const int swz = (g ^ (r & 3)) * 8;
  const int aOff = (wm * 128 + r) * 32 + swz;
  const int bOff = 8192 + (wn * 64 + r) * 32 + swz;

  f32x4 acc[8][4] = {};

#define STAGE(kt) do {                                        \
    unsigned short* tb_ = lds + (size_t)((kt) & 3) * 16384;   \
    LOAD_LDS16(gA0 + (kt) * 32, tb_ + ldsA0);                 \
    LOAD_LDS16(gA1 + (kt) * 32, tb_ + ldsA1);                 \
    LOAD_LDS16(gB0 + (kt) * 32, tb_ + 8192 + ldsA0);          \
    LOAD_LDS16(gB1 + (kt) * 32, tb_ + 8192 + ldsA1);          \
  } while (0)

#define COMPUTE(kt) do {                                                     \
    const unsigned short* tb_ = lds + (size_t)((kt) & 3) * 16384;            \
    short8 bfr[4];                                                           \
    _Pragma("unroll") for (int nj = 0; nj < 4; ++nj)                         \
      bfr[nj] = *(const short8*)(tb_ + bOff + nj * 512);                     \
    _Pragma("unroll") for (int mi = 0; mi < 8; ++mi) {                       \
      short8 afr = *(const short8*)(tb_ + aOff + mi * 512);                  \
      _Pragma("unroll") for (int nj = 0; nj < 4; ++nj)                       \
        acc[mi][nj] = __builtin_amdgcn_mfma_f32_16x16x32_bf16(               \
            afr, bfr[nj], acc[mi][nj], 0, 0, 0);                             \
    }                                                                        \
  } while (0)

  STAGE(0); STAGE(1); STAGE(2);
  asm volatile("s_waitcnt vmcnt(8)" ::: "memory");   // tile 0 landed
  __builtin_amdgcn_s_barrier();
  asm volatile("" ::: "memory");

  for (int t = 0; t < 13; ++t) {
    STAGE(t + 3);                                     // slot (t-1)&3: readers done at prev barrier
    COMPUTE(t);
    asm volatile("s_waitcnt lgkmcnt(0)" ::: "memory");  // my LDS reads done
    asm volatile("s_waitcnt vmcnt(8)" ::: "memory");    // tile t+1 landed
    __builtin_amdgcn_s_barrier();
    asm volatile("" ::: "memory");
  }
  COMPUTE(13);
  asm volatile("s_waitcnt lgkmcnt(0)" ::: "memory");
  asm volatile("s_waitcnt vmcnt(4)" ::: "memory");      // tile 14 landed
  __builtin_amdgcn_s_barrier();
  asm volatile("" ::: "memory");
  COMPUTE(14);
  asm volatile("s_waitcnt lgkmcnt(0)" ::: "memory");
  asm volatile("s_waitcnt vmcnt(0)" ::: "memory");      // tile 15 landed
  __builtin_amdgcn_s_barrier();
  asm volatile("" ::: "memory");
  COMPUTE(15);

#undef STAGE
#undef COMPUTE

  // Epilogue. C/D layout: col = lane&15, row = (lane>>4)*4 + j
  const int ldc = N;
#pragma unroll
  for (int nj = 0; nj < 4; ++nj) {
    const int col = n0 + wn * 64 + nj * 16 + r;
#pragma unroll
    for (int mi = 0; mi < 8; ++mi) {
      const int rowb = m0 + wm * 128 + mi * 16 + g * 4;
      f32x4 v = acc[mi][nj];
#pragma unroll
      for (int j = 0; j < 4; ++j) {
        float val = v[j] + bcol[nj];
        size_t off = (size_t)(rowb + j) * ldc + col;
        if (OUT_BF16) ((unsigned short*)Cv)[off] = f2bf(val);
        else          ((float*)Cv)[off] = val;
      }
    }
  }
}

// ---------------------------------------------------------------------------
// S1: scores + softmax. Thread per (m,h). q pre-scaled (Wq cast). Writes
// normalized probs f32 [m*8+h][8] (taps 5..7 zero). All loads independent.
__global__ __launch_bounds__(256) void swa_scores(
    const unsigned short* __restrict__ qkv, float* __restrict__ probs) {
  const int t = blockIdx.x * 256 + threadIdx.x;  // 0..262143
  const int h = t & 7, m = t >> 3, s = m & (S_ - 1);
  const unsigned short* base = qkv + (size_t)m * 1536 + h * 64;

  float q[64];
#pragma unroll
  for (int c = 0; c < 8; ++c) {
    short8 v = *(const short8*)(base + c * 8);
#pragma unroll
    for (int j = 0; j < 8; ++j) q[c * 8 + j] = bf2f((unsigned short)v[j]);
  }

  float sc[5];
#pragma unroll
  for (int w = 0; w < 5; ++w) {
    int s2 = s + w - 2;
    float res = -1e30f;
    if ((unsigned)s2 < (unsigned)S_) {
      const unsigned short* kp = base + (ptrdiff_t)(w - 2) * 1536 + 512;
      float a0 = 0.f, a1 = 0.f, a2 = 0.f, a3 = 0.f;
#pragma unroll
      for (int c = 0; c < 8; ++c) {
        short8 v = *(const short8*)(kp + c * 8);
        a0 += q[c * 8 + 0] * bf2f((unsigned short)v[0]);
        a1 += q[c * 8 + 1] * bf2f((unsigned short)v[1]);
        a2 += q[c * 8 + 2] * bf2f((unsigned short)v[2]);
        a3 += q[c * 8 + 3] * bf2f((unsigned short)v[3]);
        a0 += q[c * 8 + 4] * bf2f((unsigned short)v[4]);
        a1 += q[c * 8 + 5] * bf2f((unsigned short)v[5]);
        a2 += q[c * 8 + 6] * bf2f((unsigned short)v[6]);
        a3 += q[c * 8 + 7] * bf2f((unsigned short)v[7]);
      }
      res = (a0 + a1) + (a2 + a3);
    }
    sc[w] = res;
  }

  float mx = fmaxf(fmaxf(fmaxf(sc[0], sc[1]), fmaxf(sc[2], sc[3])), sc[4]);
  float e[5], sum = 0.f;
#pragma unroll
  for (int w = 0; w < 5; ++w) { e[w] = __expf(sc[w] - mx); sum += e[w]; }
  float inv = 1.0f / sum;

  float4 p03 = {e[0] * inv, e[1] * inv, e[2] * inv, e[3] * inv};
  float4 p47 = {e[4] * inv, 0.f, 0.f, 0.f};
  *(float4*)(probs + (size_t)t * 8)     = p03;
  *(float4*)(probs + (size_t)t * 8 + 4) = p47;
}

// S2: out[m][e] = sum_w p[m][h][w] * v[m+w-2][e]. Thread per (m, 8-dim chunk).
// Masked taps have p==0 exactly; OOB v reads stay inside d_ws -> contribute 0.
__global__ __launch_bounds__(256) void swa_out(
    const unsigned short* __restrict__ qkv, const float* __restrict__ probs,
    unsigned short* __restrict__ attn) {
  const int t = blockIdx.x * 256 + threadIdx.x;  // 0..2097151
  const int ec = t & 63, m = t >> 6, h = ec >> 3;
  const float* pp = probs + ((size_t)(m << 3) + h) * 8;
  float4 p03 = *(const float4*)pp;
  float p4 = pp[4];
  float pw[5] = {p03.x, p03.y, p03.z, p03.w, p4};

  const unsigned short* vbase = qkv + (size_t)m * 1536 + 1024 + ec * 8;
  float o[8] = {0.f, 0.f, 0.f, 0.f, 0.f, 0.f, 0.f, 0.f};
#pragma unroll
  for (int w = 0; w < 5; ++w) {
    short8 v = *(const short8*)(vbase + (ptrdiff_t)(w - 2) * 1536);
#pragma unroll
    for (int j = 0; j < 8; ++j) o[j] += pw[w] * bf2f((unsigned short)v[j]);
  }
  short8 ov;
#pragma unroll
  for (int j = 0; j < 8; ++j) ov[j] = (short)f2bf(o[j]);
  *(short8*)(attn + (size_t)m * 512 + ec * 8) = ov;
}

// ---------------------------------------------------------------------------
extern "C" void kernel_launch(void* const* d_in, const int* in_sizes, int n_in,
                              void* d_out, int out_size, void* d_ws, size_t ws_size,
                              hipStream_t stream) {
  const float* x  = (const float*)d_in[0];
  const float* Wq = (const float*)d_in[1];
  const float* Wk = (const float*)d_in[2];
  const float* Wv = (const float*)d_in[3];
  const float* bq = (const float*)d_in[4];
  const float* bk = (const float*)d_in[5];
  const float* bv = (const float*)d_in[6];
  const float* Wo = (const float*)d_in[7];
  const float* bo = (const float*)d_in[8];
  float* out = (float*)d_out;

  char* ws = (char*)d_ws;
  unsigned short* xb   = (unsigned short*)(ws);               // 33,554,432 B
  unsigned short* qkv  = (unsigned short*)(ws + 33554432);    // 100,663,296 B
  unsigned short* attn = (unsigned short*)(ws + 134217728);   // 33,554,432 B
  unsigned short* Wcat = (unsigned short*)(ws + 167772160);   // 1,572,864 B
  unsigned short* Wob  = (unsigned short*)(ws + 169345024);   // 524,288 B
  float* bcat          = (float*)(ws + 169869312);            // 6,144 B
  float* probs         = (float*)(ws);  // 8 MB, aliases xb (dead after GEMM1)

  cast_x_kernel<<<16384, 256, 0, stream>>>(x, xb);
  cast_w_kernel<<<1024, 256, 0, stream>>>(Wq, Wk, Wv, Wo, bq, bk, bv, Wcat, Wob, bcat);
  // QKV projection: M=32768, N=1536 -> 128x6 = 768 blocks
  gemm256<1, 6><<<768, 512, 0, stream>>>(xb, Wcat, bcat, qkv);
  // attention
  swa_scores<<<1024, 256, 0, stream>>>(qkv, probs);
  swa_out<<<8192, 256, 0, stream>>>(qkv, probs, attn);
  // output projection: M=32768, N=512 -> 128x2 = 256 blocks
  gemm256<0, 2><<<256, 512, 0, stream>>>(attn, Wob, bo, out);
}

// Round 6
// 243.114 us; speedup vs baseline: 1.3516x; 1.3516x over previous
//
#include <hip/hip_runtime.h>

#define S_ 4096

typedef __attribute__((ext_vector_type(8))) short short8;
typedef __attribute__((ext_vector_type(4))) float f32x4;

static __device__ __forceinline__ float bf2f(unsigned short u) {
  union { unsigned int i; float f; } v; v.i = ((unsigned int)u) << 16; return v.f;
}
static __device__ __forceinline__ unsigned short f2bf(float f) {
  union { float f; unsigned int i; } v; v.f = f;
  unsigned int r = v.i + 0x7FFFu + ((v.i >> 16) & 1u);
  return (unsigned short)(r >> 16);
}

#define LOAD_LDS16(g, l) __builtin_amdgcn_global_load_lds( \
    (const __attribute__((address_space(1))) void*)(g),     \
    (__attribute__((address_space(3))) void*)(l), 16, 0, 0)

// ---------------------------------------------------------------------------
__global__ __launch_bounds__(256) void cast_x_kernel(
    const float* __restrict__ x, unsigned short* __restrict__ xb) {
  int i = (blockIdx.x * 256 + threadIdx.x) * 4;
  float4 v = *(const float4*)(x + i);
  ushort4 o;
  o.x = f2bf(v.x); o.y = f2bf(v.y); o.z = f2bf(v.z); o.w = f2bf(v.w);
  *(ushort4*)(xb + i) = o;
}

// Wq/bq pre-scaled by 0.125 (= 1/sqrt(64), exact)
__global__ __launch_bounds__(256) void cast_w_kernel(
    const float* __restrict__ Wq, const float* __restrict__ Wk,
    const float* __restrict__ Wv, const float* __restrict__ Wo,
    const float* __restrict__ bq, const float* __restrict__ bk,
    const float* __restrict__ bv,
    unsigned short* __restrict__ Wcat, unsigned short* __restrict__ Wob,
    float* __restrict__ bcat) {
  int i = blockIdx.x * 256 + threadIdx.x;  // 0..262143
  Wcat[i]          = f2bf(Wq[i] * 0.125f);
  Wcat[262144 + i] = f2bf(Wk[i]);
  Wcat[524288 + i] = f2bf(Wv[i]);
  Wob[i]           = f2bf(Wo[i]);
  if (i < 512) { bcat[i] = bq[i] * 0.125f; bcat[512 + i] = bk[i]; bcat[1024 + i] = bv[i]; }
}

// ---------------------------------------------------------------------------
// C[m][n] = sum_k A[m][k]*Bw[n][k] + bias[n], K=512, row-major operands.
// BM=BN=128, BK=64, 4 waves (2x2), per-wave 64x64 (4x4 frags 16x16x32).
// Ring-2 LDS (64 KiB static -> 2 blocks/CU for barrier-hiding), counted
// vmcnt(8) prefetch of tile t+2 (never drained to 0 in main loop).
// LDS swizzle: slot sp of row holds chunk sp^(row&7) (8x16B chunks/row);
// applied on gload SOURCE (inverse) and ds_read address (both-sides, #21).
template<int OUT_BF16, int NBX>
__global__ __launch_bounds__(256, 2) void gemm128(
    const unsigned short* __restrict__ A,
    const unsigned short* __restrict__ Bw,
    const float* __restrict__ bias,
    void* __restrict__ Cv) {
  __shared__ unsigned short lds[32768];  // 2 slots x (A 8192 + B 8192) ushorts
  const int N = NBX * 128;
  const int NWG = 256 * NBX;             // (32768/128) * NBX

  const int tid = threadIdx.x;
  const int lane = tid & 63;
  const int wv = tid >> 6;        // 0..3
  const int wm = wv >> 1, wn = wv & 1;
  const int r = lane & 15, g = lane >> 4;

  // XCD-aware swizzle (NWG % 8 == 0 -> bijective)
  int id = blockIdx.x;
  id = (id & 7) * (NWG >> 3) + (id >> 3);
  const int by = id / NBX, bx = id % NBX;
  const int m0 = by * 128, n0 = bx * 128;

  // bias preload, pinned BEFORE staging so vmcnt FIFO math stays exact
  float bcol[4];
#pragma unroll
  for (int nj = 0; nj < 4; ++nj) bcol[nj] = bias[n0 + wn * 64 + nj * 16 + r];
  asm volatile("" : "+v"(bcol[0]), "+v"(bcol[1]), "+v"(bcol[2]), "+v"(bcol[3]));

  // staging: per tile 1024 chunks of 16B per operand; thread i-th call covers
  // chunk ci = i*256+tid -> row=ci>>3, slot=ci&7, src chunk = slot^(row&7).
  const unsigned short* gA[4];
  const unsigned short* gB[4];
  int ldsb[4];
#pragma unroll
  for (int i = 0; i < 4; ++i) {
    int ci = i * 256 + tid;
    int row = ci >> 3, sp = ci & 7;
    int cs = sp ^ (row & 7);
    gA[i] = A + (size_t)(m0 + row) * 512 + cs * 8;
    gB[i] = Bw + (size_t)(n0 + row) * 512 + cs * 8;
    ldsb[i] = (i * 256 + wv * 64) * 8;   // wave-uniform LDS base (ushorts)
  }

  f32x4 acc[4][4] = {};

#define STAGE(kt) do {                                         \
    unsigned short* tb_ = lds + (((kt) & 1) << 14);            \
    LOAD_LDS16(gA[0] + (kt) * 64, tb_ + ldsb[0]);              \
    LOAD_LDS16(gA[1] + (kt) * 64, tb_ + ldsb[1]);              \
    LOAD_LDS16(gA[2] + (kt) * 64, tb_ + ldsb[2]);              \
    LOAD_LDS16(gA[3] + (kt) * 64, tb_ + ldsb[3]);              \
    LOAD_LDS16(gB[0] + (kt) * 64, tb_ + 8192 + ldsb[0]);       \
    LOAD_LDS16(gB[1] + (kt) * 64, tb_ + 8192 + ldsb[1]);       \
    LOAD_LDS16(gB[2] + (kt) * 64, tb_ + 8192 + ldsb[2]);       \
    LOAD_LDS16(gB[3] + (kt) * 64, tb_ + 8192 + ldsb[3]);       \
  } while (0)

#define COMPUTE(kt) do {                                                     \
    const unsigned short* tb_ = lds + (((kt) & 1) << 14);                    \
    _Pragma("unroll") for (int ks = 0; ks < 2; ++ks) {                       \
      const int sw_ = ((ks * 4 + g) ^ (r & 7)) * 8;                          \
      short8 a_[4], b_[4];                                                   \
      _Pragma("unroll") for (int mi = 0; mi < 4; ++mi)                       \
        a_[mi] = *(const short8*)&tb_[(wm * 64 + mi * 16 + r) * 64 + sw_];   \
      _Pragma("unroll") for (int nj = 0; nj < 4; ++nj)                       \
        b_[nj] = *(const short8*)&tb_[8192 + (wn * 64 + nj * 16 + r) * 64 + sw_]; \
      _Pragma("unroll") for (int mi = 0; mi < 4; ++mi)                       \
        _Pragma("unroll") for (int nj = 0; nj < 4; ++nj)                     \
          acc[mi][nj] = __builtin_amdgcn_mfma_f32_16x16x32_bf16(             \
              a_[mi], b_[nj], acc[mi][nj], 0, 0, 0);                         \
    }                                                                        \
  } while (0)

  STAGE(0); STAGE(1);                                 // 16 loads out
  asm volatile("s_waitcnt vmcnt(8)" ::: "memory");    // tile 0 landed
  __builtin_amdgcn_s_barrier();
  asm volatile("" ::: "memory");

  for (int t = 0; t < 6; ++t) {
    COMPUTE(t);                                       // reads slot t&1
    asm volatile("s_waitcnt lgkmcnt(0)" ::: "memory");
    __builtin_amdgcn_s_barrier();                     // all reads of slot t&1 done
    asm volatile("" ::: "memory");
    STAGE(t + 2);                                     // overwrite slot t&1
    asm volatile("s_waitcnt vmcnt(8)" ::: "memory");  // tile t+1 landed (FIFO)
    __builtin_amdgcn_s_barrier();
    asm volatile("" ::: "memory");
  }
  COMPUTE(6);
  asm volatile("s_waitcnt vmcnt(0)" ::: "memory");    // tile 7 landed
  __builtin_amdgcn_s_barrier();
  asm volatile("" ::: "memory");
  COMPUTE(7);

#undef STAGE
#undef COMPUTE

  // Epilogue. C/D layout: col = lane&15, row = (lane>>4)*4 + j
  const int ldc = N;
#pragma unroll
  for (int nj = 0; nj < 4; ++nj) {
    const int col = n0 + wn * 64 + nj * 16 + r;
#pragma unroll
    for (int mi = 0; mi < 4; ++mi) {
      const int rowb = m0 + wm * 64 + mi * 16 + g * 4;
      f32x4 v = acc[mi][nj];
#pragma unroll
      for (int j = 0; j < 4; ++j) {
        float val = v[j] + bcol[nj];
        size_t off = (size_t)(rowb + j) * ldc + col;
        if (OUT_BF16) ((unsigned short*)Cv)[off] = f2bf(val);
        else          ((float*)Cv)[off] = val;
      }
    }
  }
}

// ---------------------------------------------------------------------------
// Fused sliding-window attention. One WAVE per m (= b*S+s), all 8 heads.
// lane = h*8+c (h=lane>>3, c=lane&7): every q/k/v access is lane*16B ->
// perfectly coalesced 1KB per wave-instruction. Dot over D=64 is reduced
// across the 8 c-lanes of the h-group via shfl_xor(1,2,4).
__global__ __launch_bounds__(256) void swa_fused(
    const unsigned short* __restrict__ qkv, unsigned short* __restrict__ attn) {
  const int m = (blockIdx.x * 256 + threadIdx.x) >> 6;  // 0..32767
  const int lane = threadIdx.x & 63;
  const int s = m & (S_ - 1);
  const unsigned short* base = qkv + (size_t)m * 1536 + lane * 8;

  float q[8];
  {
    short8 qv = *(const short8*)base;
#pragma unroll
    for (int j = 0; j < 8; ++j) q[j] = bf2f((unsigned short)qv[j]);
  }

  float sc[5];
#pragma unroll
  for (int w = 0; w < 5; ++w) {
    int s2 = s + w - 2;
    float p = -1e30f;
    if ((unsigned)s2 < (unsigned)S_) {          // wave-uniform
      short8 kv = *(const short8*)(base + (ptrdiff_t)(w - 2) * 1536 + 512);
      float a = 0.f;
#pragma unroll
      for (int j = 0; j < 8; ++j) a += q[j] * bf2f((unsigned short)kv[j]);
      a += __shfl_xor(a, 1);
      a += __shfl_xor(a, 2);
      a += __shfl_xor(a, 4);                    // h-group (8 lanes) reduce
      p = a;
    }
    sc[w] = p;
  }

  float mx = fmaxf(fmaxf(fmaxf(sc[0], sc[1]), fmaxf(sc[2], sc[3])), sc[4]);
  float e[5], sum = 0.f;
#pragma unroll
  for (int w = 0; w < 5; ++w) { e[w] = __expf(sc[w] - mx); sum += e[w]; }
  float inv = 1.0f / sum;

  float o[8] = {0.f, 0.f, 0.f, 0.f, 0.f, 0.f, 0.f, 0.f};
#pragma unroll
  for (int w = 0; w < 5; ++w) {
    int s2 = s + w - 2;
    if ((unsigned)s2 < (unsigned)S_) {
      short8 vv = *(const short8*)(base + (ptrdiff_t)(w - 2) * 1536 + 1024);
      float pw = e[w] * inv;
#pragma unroll
      for (int j = 0; j < 8; ++j) o[j] += pw * bf2f((unsigned short)vv[j]);
    }
  }

  short8 ov;
#pragma unroll
  for (int j = 0; j < 8; ++j) ov[j] = (short)f2bf(o[j]);
  *(short8*)(attn + (size_t)m * 512 + lane * 8) = ov;
}

// ---------------------------------------------------------------------------
extern "C" void kernel_launch(void* const* d_in, const int* in_sizes, int n_in,
                              void* d_out, int out_size, void* d_ws, size_t ws_size,
                              hipStream_t stream) {
  const float* x  = (const float*)d_in[0];
  const float* Wq = (const float*)d_in[1];
  const float* Wk = (const float*)d_in[2];
  const float* Wv = (const float*)d_in[3];
  const float* bq = (const float*)d_in[4];
  const float* bk = (const float*)d_in[5];
  const float* bv = (const float*)d_in[6];
  const float* Wo = (const float*)d_in[7];
  const float* bo = (const float*)d_in[8];
  float* out = (float*)d_out;

  char* ws = (char*)d_ws;
  unsigned short* xb   = (unsigned short*)(ws);               // 33,554,432 B
  unsigned short* qkv  = (unsigned short*)(ws + 33554432);    // 100,663,296 B
  unsigned short* attn = (unsigned short*)(ws + 134217728);   // 33,554,432 B
  unsigned short* Wcat = (unsigned short*)(ws + 167772160);   // 1,572,864 B
  unsigned short* Wob  = (unsigned short*)(ws + 169345024);   // 524,288 B
  float* bcat          = (float*)(ws + 169869312);            // 6,144 B

  cast_x_kernel<<<16384, 256, 0, stream>>>(x, xb);
  cast_w_kernel<<<1024, 256, 0, stream>>>(Wq, Wk, Wv, Wo, bq, bk, bv, Wcat, Wob, bcat);
  // QKV projection: M=32768, N=1536 -> 256 by x 12 bx = 3072 blocks
  gemm128<1, 12><<<3072, 256, 0, stream>>>(xb, Wcat, bcat, qkv);
  // fused sliding-window attention: one wave per m
  swa_fused<<<8192, 256, 0, stream>>>(qkv, attn);
  // output projection: M=32768, N=512 -> 256 by x 4 bx = 1024 blocks
  gemm128<0, 4><<<1024, 256, 0, stream>>>(attn, Wob, bo, out);
}